// Round 12
// baseline (162.371 us; speedup 1.0000x reference)
//
#include <hip/hip_runtime.h>

// GCN 2-layer. R19 = R18 (159.4us verified best) + register-resident k_csr.
// R18 post-mortem: wave-scan neutral-positive; R17's +16.4 fully attributed to
// fused-final's per-block agent-scope __threadfence() (HW RULE #4 confirmed:
// cross-XCD L2 writeback storms). Re-decomposing R14 (174.5) vs R17 (177.3):
// reg-csr + 8-way was actually -3us — wrongly convicted in R14. Its mechanism
// (each thread's csr edges fit 2xuint4+tail regs; count AND place from regs ->
// deletes csr's second 16KB/block global read) is sound and R14-correctness-
// proven. This round isolates it on top of R18.
//  k_sort  : bucket sort by dst>>7, 256 blocks (512 amplifies writes, R16)
//  k_csr   : reg-resident count/scan(wave)/place -> sorted srcs + rptr + dinv/u
//  k_agg1  : atomic-free segmented sum of u[src] (4-way unrolled) + MLP -> w
//  k_agg2  : segmented float2 sum (4-way unrolled) + log_softmax + block partial
//  k_reduce_final : sum partials + 1/N   (NO fences anywhere in hot path)
// packed word (pre-sort): bits[16:0]=src, bits[23:17]=dst&127; post-sort: src.

#define TPB 512
#define SORT_BLK 256
#define BSHIFT 7
#define BNODES 128
#define MAXBUCK 1024
#define BSTRIDE 6144      // words per bucket region; mean 4092, sigma ~64 -> 32 sigma

// ---------------- bucket sort (count+place fused, atomic reservation) --------

__global__ __launch_bounds__(TPB) void k_sort(const int* __restrict__ ei, int E, int epb,
                                              int nbuck, int* __restrict__ gcur,
                                              unsigned* __restrict__ packed) {
    __shared__ int h[MAXBUCK];
    for (int b = threadIdx.x; b < nbuck; b += TPB) h[b] = 0;
    __syncthreads();
    const int4* d4 = (const int4*)(ei + E);
    int nq = epb >> 2;
    int q0 = blockIdx.x * nq;
    for (int j = threadIdx.x; j < nq; j += TPB) {
        int q = q0 + j;
        int e = q << 2;
        if (e + 3 < E) {
            int4 v = d4[q];
            atomicAdd(&h[v.x >> BSHIFT], 1);
            atomicAdd(&h[v.y >> BSHIFT], 1);
            atomicAdd(&h[v.z >> BSHIFT], 1);
            atomicAdd(&h[v.w >> BSHIFT], 1);
        } else {
            for (int k = 0; k < 4; ++k)
                if (e + k < E) atomicAdd(&h[(ei + E)[e + k] >> BSHIFT], 1);
        }
    }
    __syncthreads();
    for (int b = threadIdx.x; b < nbuck; b += TPB) {
        int c = h[b];
        h[b] = c ? atomicAdd(&gcur[b], c) : 0;
    }
    __syncthreads();
    const int4* s4 = (const int4*)ei;
    for (int j = threadIdx.x; j < nq; j += TPB) {
        int q = q0 + j;
        int e = q << 2;
        if (e + 3 < E) {
            int4 vs = s4[q];
            int4 vd = d4[q];
            int b, p;
            b = vd.x >> BSHIFT; p = atomicAdd(&h[b], 1);
            packed[b * BSTRIDE + p] = ((unsigned)(vd.x & (BNODES - 1)) << 17) | (unsigned)vs.x;
            b = vd.y >> BSHIFT; p = atomicAdd(&h[b], 1);
            packed[b * BSTRIDE + p] = ((unsigned)(vd.y & (BNODES - 1)) << 17) | (unsigned)vs.y;
            b = vd.z >> BSHIFT; p = atomicAdd(&h[b], 1);
            packed[b * BSTRIDE + p] = ((unsigned)(vd.z & (BNODES - 1)) << 17) | (unsigned)vs.z;
            b = vd.w >> BSHIFT; p = atomicAdd(&h[b], 1);
            packed[b * BSTRIDE + p] = ((unsigned)(vd.w & (BNODES - 1)) << 17) | (unsigned)vs.w;
        } else {
            for (int k = 0; k < 4; ++k) {
                int ee = e + k;
                if (ee < E) {
                    int s = ei[ee], d = ei[E + ee];
                    int b = d >> BSHIFT;
                    int p = atomicAdd(&h[b], 1);
                    packed[b * BSTRIDE + p] = ((unsigned)(d & (BNODES - 1)) << 17) | (unsigned)s;
                }
            }
        }
    }
}

// ------- per-bucket CSR build: register-resident edges, wave scan -------

__global__ __launch_bounds__(TPB) void k_csr(unsigned* __restrict__ packed,
                                             const int* __restrict__ gcur,
                                             const float* __restrict__ x,
                                             float* __restrict__ dinv,
                                             float* __restrict__ u,
                                             int* __restrict__ rptr, int N) {
    __shared__ int cnt[8][BNODES];
    __shared__ int eptr[BNODES];
    __shared__ unsigned stage[BSTRIDE];
    const int tid = threadIdx.x;
    for (int k = tid; k < 8 * BNODES; k += TPB) ((int*)cnt)[k] = 0;
    __syncthreads();
    const int b = blockIdx.x;
    const int sz = gcur[b];
    unsigned* base = packed + (size_t)b * BSTRIDE;
    const uint4* base4 = (const uint4*)base;
    const int wv = tid >> 6;
    const int nq4 = sz >> 2;
    const int half = nq4 >> 1;              // half <= BSTRIDE/8 = 768 -> <= 2 iters/thread
    // ---- load this thread's edges ONCE into registers ----
    uint4 rp[2], rq[2];
    int nit = 0;
    #pragma unroll
    for (int it = 0; it < 2; ++it) {
        int j = tid + it * TPB;
        if (j < half) {
            rp[it] = base4[j];
            rq[it] = base4[j + half];
            nit = it + 1;
        }
    }
    unsigned rt = 0; int havet = 0;
    {
        int j = half * 8 + tid;             // tail <= 7 words -> <= 1 per thread
        if (j < sz) { rt = base[j]; havet = 1; }
    }
    // ---- count pass (from registers) ----
    #pragma unroll
    for (int it = 0; it < 2; ++it) {
        if (it < nit) {
            uint4 p = rp[it], q = rq[it];
            atomicAdd(&cnt[wv][(p.x >> 17) & 127], 1);
            atomicAdd(&cnt[wv][(p.y >> 17) & 127], 1);
            atomicAdd(&cnt[wv][(p.z >> 17) & 127], 1);
            atomicAdd(&cnt[wv][(p.w >> 17) & 127], 1);
            atomicAdd(&cnt[wv][(q.x >> 17) & 127], 1);
            atomicAdd(&cnt[wv][(q.y >> 17) & 127], 1);
            atomicAdd(&cnt[wv][(q.z >> 17) & 127], 1);
            atomicAdd(&cnt[wv][(q.w >> 17) & 127], 1);
        }
    }
    if (havet) atomicAdd(&cnt[wv][(rt >> 17) & 127], 1);
    __syncthreads();
    // ---- per-node totals ----
    int tot = 0;
    if (tid < BNODES) {
        #pragma unroll
        for (int c = 0; c < 8; ++c) tot += cnt[c][tid];
        eptr[tid] = tot;
    }
    __syncthreads();
    // ---- single-wave inclusive scan of 128 values ----
    if (tid < 64) {
        int v0 = eptr[tid], v1 = eptr[tid + 64];
        #pragma unroll
        for (int off = 1; off < 64; off <<= 1) {
            int t0 = __shfl_up(v0, off, 64);
            int t1 = __shfl_up(v1, off, 64);
            if (tid >= off) { v0 += t0; v1 += t1; }
        }
        v1 += __shfl(v0, 63, 64);
        eptr[tid] = v0;
        eptr[tid + 64] = v1;
    }
    __syncthreads();
    // ---- exclusive offsets, per-wave cursor bases, dinv/u, rptr ----
    if (tid < BNODES) {
        int ex = eptr[tid] - tot;
        int run = ex;
        #pragma unroll
        for (int c = 0; c < 8; ++c) { int v = cnt[c][tid]; cnt[c][tid] = run; run += v; }
        rptr[b * BNODES + tid] = ex;
        int node = (b << BSHIFT) + tid;
        if (node < N) {
            float di = rsqrtf((float)(tot + 1));   // +1 self-loop
            dinv[node] = di;
            u[node] = di * x[node];
        }
    }
    __syncthreads();
    // ---- placement pass (from registers, same per-wave partition) ----
    #pragma unroll
    for (int it = 0; it < 2; ++it) {
        if (it < nit) {
            uint4 p = rp[it], q = rq[it];
            int pos;
            pos = atomicAdd(&cnt[wv][(p.x >> 17) & 127], 1); stage[pos] = p.x & 0x1FFFF;
            pos = atomicAdd(&cnt[wv][(p.y >> 17) & 127], 1); stage[pos] = p.y & 0x1FFFF;
            pos = atomicAdd(&cnt[wv][(p.z >> 17) & 127], 1); stage[pos] = p.z & 0x1FFFF;
            pos = atomicAdd(&cnt[wv][(p.w >> 17) & 127], 1); stage[pos] = p.w & 0x1FFFF;
            pos = atomicAdd(&cnt[wv][(q.x >> 17) & 127], 1); stage[pos] = q.x & 0x1FFFF;
            pos = atomicAdd(&cnt[wv][(q.y >> 17) & 127], 1); stage[pos] = q.y & 0x1FFFF;
            pos = atomicAdd(&cnt[wv][(q.z >> 17) & 127], 1); stage[pos] = q.z & 0x1FFFF;
            pos = atomicAdd(&cnt[wv][(q.w >> 17) & 127], 1); stage[pos] = q.w & 0x1FFFF;
        }
    }
    if (havet) {
        int pos = atomicAdd(&cnt[wv][(rt >> 17) & 127], 1);
        stage[pos] = rt & 0x1FFFF;
    }
    __syncthreads();
    // ---- coalesced in-place writeback of sorted srcs ----
    for (int k = tid; k < sz; k += TPB) base[k] = stage[k];
}

// ------- layer-1: segmented sum (4-way unrolled gathers) + MLP -> w -------

__global__ __launch_bounds__(TPB) void k_agg1(const unsigned* __restrict__ sorted,
                                              const int* __restrict__ gcur,
                                              const int* __restrict__ rptr,
                                              const float* __restrict__ dinv,
                                              const float* __restrict__ u,
                                              const float* __restrict__ W1,
                                              const float* __restrict__ b1,
                                              const float* __restrict__ W2,
                                              float2* __restrict__ w, int N) {
    __shared__ float sW1[64], sb1[64], sW2[128];
    __shared__ int sptr[BNODES + 1];
    int b = blockIdx.x;
    if (threadIdx.x < 64) { sW1[threadIdx.x] = W1[threadIdx.x]; sb1[threadIdx.x] = b1[threadIdx.x]; }
    else if (threadIdx.x < 192) sW2[threadIdx.x - 64] = W2[threadIdx.x - 64];
    if (threadIdx.x < BNODES) sptr[threadIdx.x] = rptr[b * BNODES + threadIdx.x];
    if (threadIdx.x == 0) sptr[BNODES] = gcur[b];
    __syncthreads();
    int t = threadIdx.x >> 2, k = threadIdx.x & 3;
    const unsigned* base = sorted + (size_t)b * BSTRIDE;
    int s0 = sptr[t], s1 = sptr[t + 1];
    float s = 0.f;
    int j = s0 + k;
    for (; j + 12 < s1; j += 16) {
        unsigned i0 = base[j], i1 = base[j + 4], i2 = base[j + 8], i3 = base[j + 12];
        float a0 = u[i0], a1 = u[i1], a2 = u[i2], a3 = u[i3];
        s += (a0 + a1) + (a2 + a3);
    }
    for (; j < s1; j += 4) s += u[base[j]];
    s += __shfl_xor(s, 1, 64);
    s += __shfl_xor(s, 2, 64);
    int node = (b << BSHIFT) + t;
    if (k == 0 && node < N) {
        float di = dinv[node];
        float sv = di * (s + u[node]);           // self-loop term dinv*u
        float z0 = 0.f, z1 = 0.f;
        #pragma unroll
        for (int jj = 0; jj < 64; ++jj) {
            float h = fmaxf(fmaf(sv, sW1[jj], sb1[jj]), 0.f);
            z0 = fmaf(h, sW2[2 * jj], z0);
            z1 = fmaf(h, sW2[2 * jj + 1], z1);
        }
        w[node] = make_float2(di * z0, di * z1); // pre-scaled by dinv[src]
    }
}

// ---- layer-2: segmented float2 sum (4-way unrolled) + log_softmax + partial ----

__global__ __launch_bounds__(TPB) void k_agg2(const unsigned* __restrict__ sorted,
                                              const int* __restrict__ gcur,
                                              const int* __restrict__ rptr,
                                              const float* __restrict__ dinv,
                                              const float2* __restrict__ w,
                                              const float* __restrict__ b2,
                                              float* __restrict__ accum, int N) {
    __shared__ int sptr[BNODES + 1];
    int b = blockIdx.x;
    if (threadIdx.x < BNODES) sptr[threadIdx.x] = rptr[b * BNODES + threadIdx.x];
    if (threadIdx.x == 0) sptr[BNODES] = gcur[b];
    __syncthreads();
    int t = threadIdx.x >> 2, k = threadIdx.x & 3;
    const unsigned* base = sorted + (size_t)b * BSTRIDE;
    int s0 = sptr[t], s1 = sptr[t + 1];
    float sx = 0.f, sy = 0.f;
    int j = s0 + k;
    for (; j + 12 < s1; j += 16) {
        unsigned i0 = base[j], i1 = base[j + 4], i2 = base[j + 8], i3 = base[j + 12];
        float2 v0 = w[i0], v1 = w[i1], v2 = w[i2], v3 = w[i3];
        sx += (v0.x + v1.x) + (v2.x + v3.x);
        sy += (v0.y + v1.y) + (v2.y + v3.y);
    }
    for (; j < s1; j += 4) {
        float2 v = w[base[j]];
        sx += v.x;
        sy += v.y;
    }
    sx += __shfl_xor(sx, 1, 64); sx += __shfl_xor(sx, 2, 64);
    sy += __shfl_xor(sy, 1, 64); sy += __shfl_xor(sy, 2, 64);
    int node = (b << BSHIFT) + t;
    float l0 = 0.f, l1 = 0.f;
    if (k == 0 && node < N) {
        float di = dinv[node];
        float2 wi = w[node];
        float a0 = di * (sx + wi.x) + b2[0];
        float a1 = di * (sy + wi.y) + b2[1];
        float m = fmaxf(a0, a1);
        float lse = m + logf(expf(a0 - m) + expf(a1 - m));
        l0 = a0 - lse;
        l1 = a1 - lse;
    }
    #pragma unroll
    for (int off = 32; off > 0; off >>= 1) {
        l0 += __shfl_down(l0, off, 64);
        l1 += __shfl_down(l1, off, 64);
    }
    __shared__ float r0[TPB / 64], r1[TPB / 64];
    int wid = threadIdx.x >> 6, lane = threadIdx.x & 63;
    if (lane == 0) { r0[wid] = l0; r1[wid] = l1; }
    __syncthreads();
    if (threadIdx.x == 0) {
        float t0 = 0.f, t1 = 0.f;
        #pragma unroll
        for (int kk = 0; kk < TPB / 64; ++kk) { t0 += r0[kk]; t1 += r1[kk]; }
        accum[2 * b]     = t0;   // private slot, plain store, NO fence
        accum[2 * b + 1] = t1;
    }
}

// ---------------- final reduction over per-block partials ----------------

#define RTPB 1024
__global__ __launch_bounds__(RTPB) void k_reduce_final(const float* __restrict__ accum,
                                                       int nb, float* __restrict__ out,
                                                       float invN) {
    float t0 = 0.f, t1 = 0.f;
    for (int i = threadIdx.x; i < nb; i += RTPB) {
        t0 += accum[2 * i];
        t1 += accum[2 * i + 1];
    }
    #pragma unroll
    for (int off = 32; off > 0; off >>= 1) {
        t0 += __shfl_down(t0, off, 64);
        t1 += __shfl_down(t1, off, 64);
    }
    __shared__ float s0[RTPB / 64], s1[RTPB / 64];
    int wid = threadIdx.x >> 6, lane = threadIdx.x & 63;
    if (lane == 0) { s0[wid] = t0; s1[wid] = t1; }
    __syncthreads();
    if (threadIdx.x == 0) {
        float a = 0.f, b = 0.f;
        #pragma unroll
        for (int k = 0; k < RTPB / 64; ++k) { a += s0[k]; b += s1[k]; }
        out[0] = a * invN;
        out[1] = b * invN;
    }
}

__global__ void k_finalize(const float* __restrict__ accum, float* __restrict__ out, float invN) {
    out[0] = accum[0] * invN;
    out[1] = accum[1] * invN;
}

// ---------------- fallback (global-atomic path) ----------------

#define FTPB 256
__global__ void k_hist(const int* __restrict__ dst, int E, int* __restrict__ deg) {
    int e = blockIdx.x * FTPB + threadIdx.x;
    if (e < E) atomicAdd(&deg[dst[e]], 1);
}
__global__ void k_dinv_u(const int* __restrict__ deg, const float* __restrict__ x,
                         float* __restrict__ dinv, float* __restrict__ u, int N) {
    int i = blockIdx.x * FTPB + threadIdx.x;
    if (i < N) {
        float di = rsqrtf((float)(deg[i] + 1));
        dinv[i] = di;
        u[i] = di * x[i];
    }
}
__global__ void k_scatter1(const int* __restrict__ ei, int E,
                           const float* __restrict__ u, float* __restrict__ t) {
    int e = blockIdx.x * FTPB + threadIdx.x;
    if (e < E) atomicAdd(&t[ei[E + e]], u[ei[e]]);
}
__global__ void k_node_mid_fb(const float* __restrict__ dinv, const float* __restrict__ u,
                              const float* __restrict__ t,
                              const float* __restrict__ W1, const float* __restrict__ b1,
                              const float* __restrict__ W2, float2* __restrict__ w, int N) {
    __shared__ float sW1[64], sb1[64], sW2[128];
    if (threadIdx.x < 64) { sW1[threadIdx.x] = W1[threadIdx.x]; sb1[threadIdx.x] = b1[threadIdx.x]; }
    if (threadIdx.x < 128) sW2[threadIdx.x] = W2[threadIdx.x];
    __syncthreads();
    int i = blockIdx.x * FTPB + threadIdx.x;
    if (i < N) {
        float di = dinv[i];
        float s = di * (t[i] + u[i]);
        float z0 = 0.f, z1 = 0.f;
        #pragma unroll
        for (int j = 0; j < 64; ++j) {
            float h = fmaxf(fmaf(s, sW1[j], sb1[j]), 0.f);
            z0 = fmaf(h, sW2[2 * j], z0);
            z1 = fmaf(h, sW2[2 * j + 1], z1);
        }
        w[i] = make_float2(di * z0, di * z1);
    }
}
__global__ void k_scatter2(const int* __restrict__ ei, int E,
                           const float2* __restrict__ w, float* __restrict__ acc) {
    int e = blockIdx.x * FTPB + threadIdx.x;
    if (e < E) {
        float2 ws = w[ei[e]];
        int d = ei[E + e];
        atomicAdd(&acc[2 * d], ws.x);
        atomicAdd(&acc[2 * d + 1], ws.y);
    }
}
__global__ void k_node_out_fb(const float* __restrict__ dinv, const float2* __restrict__ w,
                              const float2* __restrict__ acc, const float* __restrict__ b2,
                              float* __restrict__ accum, int N) {
    int i = blockIdx.x * FTPB + threadIdx.x;
    float l0 = 0.f, l1 = 0.f;
    if (i < N) {
        float di = dinv[i];
        float2 a = acc[i];
        float2 ww = w[i];
        float a0 = di * (a.x + ww.x) + b2[0];
        float a1 = di * (a.y + ww.y) + b2[1];
        float m = fmaxf(a0, a1);
        float lse = m + logf(expf(a0 - m) + expf(a1 - m));
        l0 = a0 - lse;
        l1 = a1 - lse;
    }
    #pragma unroll
    for (int off = 32; off > 0; off >>= 1) {
        l0 += __shfl_down(l0, off, 64);
        l1 += __shfl_down(l1, off, 64);
    }
    __shared__ float s0[FTPB / 64], s1[FTPB / 64];
    int wid = threadIdx.x >> 6, lane = threadIdx.x & 63;
    if (lane == 0) { s0[wid] = l0; s1[wid] = l1; }
    __syncthreads();
    if (threadIdx.x == 0) {
        float t0 = 0.f, t1 = 0.f;
        #pragma unroll
        for (int k = 0; k < FTPB / 64; ++k) { t0 += s0[k]; t1 += s1[k]; }
        atomicAdd(&accum[0], t0);
        atomicAdd(&accum[1], t1);
    }
}

extern "C" void kernel_launch(void* const* d_in, const int* in_sizes, int n_in,
                              void* d_out, int out_size, void* d_ws, size_t ws_size,
                              hipStream_t stream) {
    const float* x  = (const float*)d_in[0];
    const int*   ei = (const int*)d_in[1];
    const float* W1 = (const float*)d_in[2];
    const float* b1 = (const float*)d_in[3];
    const float* W2 = (const float*)d_in[4];
    const float* b2 = (const float*)d_in[5];
    float* out = (float*)d_out;

    const int N = in_sizes[0];
    const int E = in_sizes[1] / 2;
    const int nbuck = (N + BNODES - 1) >> BSHIFT;
    const int gridN = (N + FTPB - 1) / FTPB;
    const int gridE = (E + FTPB - 1) / FTPB;

    size_t offPacked = 0;
    size_t offW      = offPacked + (size_t)nbuck * BSTRIDE * 4;
    size_t offDinv   = offW + (size_t)N * 8;
    size_t offU      = offDinv + (size_t)N * 4;
    size_t offGcur   = offU + (size_t)N * 4;
    size_t offAccum  = offGcur + (size_t)nbuck * 4;
    size_t offRptr   = offAccum + (size_t)2 * nbuck * 4;
    size_t need      = offRptr + (size_t)nbuck * BNODES * 4;

    if (ws_size >= need && nbuck <= MAXBUCK && N <= (1 << 17)) {
        unsigned* packed = (unsigned*)((char*)d_ws + offPacked);
        float2*   w      = (float2*)((char*)d_ws + offW);
        float*    dinv   = (float*)((char*)d_ws + offDinv);
        float*    u      = (float*)((char*)d_ws + offU);
        int*      gcur   = (int*)((char*)d_ws + offGcur);
        float*    accum  = (float*)((char*)d_ws + offAccum);
        int*      rptr   = (int*)((char*)d_ws + offRptr);

        hipMemsetAsync(gcur, 0, (size_t)nbuck * 4, stream);

        int epb = (((E + SORT_BLK - 1) / SORT_BLK) + 3) & ~3;

        k_sort<<<SORT_BLK, TPB, 0, stream>>>(ei, E, epb, nbuck, gcur, packed);
        k_csr<<<nbuck, TPB, 0, stream>>>(packed, gcur, x, dinv, u, rptr, N);
        k_agg1<<<nbuck, TPB, 0, stream>>>(packed, gcur, rptr, dinv, u, W1, b1, W2, w, N);
        k_agg2<<<nbuck, TPB, 0, stream>>>(packed, gcur, rptr, dinv, (const float2*)w, b2, accum, N);
        k_reduce_final<<<1, RTPB, 0, stream>>>(accum, nbuck, out, 1.0f / (float)N);
    } else {
        int*   deg   = (int*)d_ws;
        float* t     = (float*)(deg + N);
        float* acc   = t + N;
        float* accum = acc + 2 * N;
        float* dinv  = accum + 2;
        float* u     = dinv + N;
        float2* w    = (float2*)(u + N);
        hipMemsetAsync(d_ws, 0, (size_t)(4 * N + 2) * sizeof(float), stream);
        k_hist<<<gridE, FTPB, 0, stream>>>(ei + E, E, deg);
        k_dinv_u<<<gridN, FTPB, 0, stream>>>(deg, x, dinv, u, N);
        k_scatter1<<<gridE, FTPB, 0, stream>>>(ei, E, u, t);
        k_node_mid_fb<<<gridN, FTPB, 0, stream>>>(dinv, u, t, W1, b1, W2, w, N);
        k_scatter2<<<gridE, FTPB, 0, stream>>>(ei, E, w, acc);
        k_node_out_fb<<<gridN, FTPB, 0, stream>>>(dinv, w, (const float2*)acc, b2, accum, N);
        k_finalize<<<1, 64, 0, stream>>>(accum, out, 1.0f / (float)N);
    }
}

// Round 13
// 157.253 us; speedup vs baseline: 1.0325x; 1.0325x over previous
//
#include <hip/hip_runtime.h>

// GCN 2-layer. R20 = R18 (159.4 best) with csr split into count / place+agg1.
// R19 post-mortem: reg-csr +3us (falsified — the 2nd packed read was L2-cheap;
// register pressure across 5 barriers was not). R18 stands as best.
// R20 lever: agg1 re-read the sorted array from global although csr had it in
// LDS. Split: k_count (count + wave-scan + rptr/dinv/u; no stage -> tiny LDS,
// high occupancy) and k_place_agg1 (placement into LDS stage via SHARED
// cursors seeded from rptr [R12-proven], aggregate u[stage[j]] DIRECTLY from
// LDS, MLP -> w, then coalesced writeback of sorted srcs for agg2). Same 5
// dispatches, agg1's 12.8MB global sorted-read becomes LDS reads, both loops
// lose the per-wave partition coupling (plain grid-stride).
//  k_sort -> k_count -> k_place_agg1 -> k_agg2 -> k_reduce_final. No fences.
// packed word (pre-sort): bits[16:0]=src, bits[23:17]=dst&127; post-sort: src.

#define TPB 512
#define SORT_BLK 256
#define BSHIFT 7
#define BNODES 128
#define MAXBUCK 1024
#define BSTRIDE 6144      // words per bucket region; mean 4092, sigma ~64 -> 32 sigma

// ---------------- bucket sort (count+place fused, atomic reservation) --------

__global__ __launch_bounds__(TPB) void k_sort(const int* __restrict__ ei, int E, int epb,
                                              int nbuck, int* __restrict__ gcur,
                                              unsigned* __restrict__ packed) {
    __shared__ int h[MAXBUCK];
    for (int b = threadIdx.x; b < nbuck; b += TPB) h[b] = 0;
    __syncthreads();
    const int4* d4 = (const int4*)(ei + E);
    int nq = epb >> 2;
    int q0 = blockIdx.x * nq;
    for (int j = threadIdx.x; j < nq; j += TPB) {
        int q = q0 + j;
        int e = q << 2;
        if (e + 3 < E) {
            int4 v = d4[q];
            atomicAdd(&h[v.x >> BSHIFT], 1);
            atomicAdd(&h[v.y >> BSHIFT], 1);
            atomicAdd(&h[v.z >> BSHIFT], 1);
            atomicAdd(&h[v.w >> BSHIFT], 1);
        } else {
            for (int k = 0; k < 4; ++k)
                if (e + k < E) atomicAdd(&h[(ei + E)[e + k] >> BSHIFT], 1);
        }
    }
    __syncthreads();
    for (int b = threadIdx.x; b < nbuck; b += TPB) {
        int c = h[b];
        h[b] = c ? atomicAdd(&gcur[b], c) : 0;
    }
    __syncthreads();
    const int4* s4 = (const int4*)ei;
    for (int j = threadIdx.x; j < nq; j += TPB) {
        int q = q0 + j;
        int e = q << 2;
        if (e + 3 < E) {
            int4 vs = s4[q];
            int4 vd = d4[q];
            int b, p;
            b = vd.x >> BSHIFT; p = atomicAdd(&h[b], 1);
            packed[b * BSTRIDE + p] = ((unsigned)(vd.x & (BNODES - 1)) << 17) | (unsigned)vs.x;
            b = vd.y >> BSHIFT; p = atomicAdd(&h[b], 1);
            packed[b * BSTRIDE + p] = ((unsigned)(vd.y & (BNODES - 1)) << 17) | (unsigned)vs.y;
            b = vd.z >> BSHIFT; p = atomicAdd(&h[b], 1);
            packed[b * BSTRIDE + p] = ((unsigned)(vd.z & (BNODES - 1)) << 17) | (unsigned)vs.z;
            b = vd.w >> BSHIFT; p = atomicAdd(&h[b], 1);
            packed[b * BSTRIDE + p] = ((unsigned)(vd.w & (BNODES - 1)) << 17) | (unsigned)vs.w;
        } else {
            for (int k = 0; k < 4; ++k) {
                int ee = e + k;
                if (ee < E) {
                    int s = ei[ee], d = ei[E + ee];
                    int b = d >> BSHIFT;
                    int p = atomicAdd(&h[b], 1);
                    packed[b * BSTRIDE + p] = ((unsigned)(d & (BNODES - 1)) << 17) | (unsigned)s;
                }
            }
        }
    }
}

// ------- per-bucket count -> rptr + dinv + u (no staging; tiny LDS) -------

__global__ __launch_bounds__(TPB) void k_count(const unsigned* __restrict__ packed,
                                               const int* __restrict__ gcur,
                                               const float* __restrict__ x,
                                               float* __restrict__ dinv,
                                               float* __restrict__ u,
                                               int* __restrict__ rptr, int N) {
    __shared__ int cnt[8][BNODES];
    __shared__ int eptr[BNODES];
    const int tid = threadIdx.x;
    for (int k = tid; k < 8 * BNODES; k += TPB) ((int*)cnt)[k] = 0;
    __syncthreads();
    const int b = blockIdx.x;
    const int sz = gcur[b];
    const unsigned* base = packed + (size_t)b * BSTRIDE;
    const uint4* base4 = (const uint4*)base;
    const int wv = tid >> 6;
    const int nq4 = sz >> 2;
    for (int j = tid; j < nq4; j += TPB) {
        uint4 p = base4[j];
        atomicAdd(&cnt[wv][(p.x >> 17) & 127], 1);
        atomicAdd(&cnt[wv][(p.y >> 17) & 127], 1);
        atomicAdd(&cnt[wv][(p.z >> 17) & 127], 1);
        atomicAdd(&cnt[wv][(p.w >> 17) & 127], 1);
    }
    for (int j = (nq4 << 2) + tid; j < sz; j += TPB)
        atomicAdd(&cnt[wv][(base[j] >> 17) & 127], 1);
    __syncthreads();
    int tot = 0;
    if (tid < BNODES) {
        #pragma unroll
        for (int c = 0; c < 8; ++c) tot += cnt[c][tid];
        eptr[tid] = tot;
    }
    __syncthreads();
    // ---- single-wave inclusive scan of 128 values ----
    if (tid < 64) {
        int v0 = eptr[tid], v1 = eptr[tid + 64];
        #pragma unroll
        for (int off = 1; off < 64; off <<= 1) {
            int t0 = __shfl_up(v0, off, 64);
            int t1 = __shfl_up(v1, off, 64);
            if (tid >= off) { v0 += t0; v1 += t1; }
        }
        v1 += __shfl(v0, 63, 64);
        eptr[tid] = v0;
        eptr[tid + 64] = v1;
    }
    __syncthreads();
    if (tid < BNODES) {
        int ex = eptr[tid] - tot;
        rptr[b * BNODES + tid] = ex;
        int node = (b << BSHIFT) + tid;
        if (node < N) {
            float di = rsqrtf((float)(tot + 1));   // +1 self-loop
            dinv[node] = di;
            u[node] = di * x[node];
        }
    }
}

// -- placement (shared cursors) + agg1 FROM LDS + MLP + sorted writeback --

__global__ __launch_bounds__(TPB) void k_place_agg1(unsigned* __restrict__ packed,
                                                    const int* __restrict__ gcur,
                                                    const int* __restrict__ rptr,
                                                    const float* __restrict__ dinv,
                                                    const float* __restrict__ u,
                                                    const float* __restrict__ W1,
                                                    const float* __restrict__ b1,
                                                    const float* __restrict__ W2,
                                                    float2* __restrict__ w, int N) {
    __shared__ unsigned stage[BSTRIDE];
    __shared__ int sptr[BNODES + 1];
    __shared__ int cur[BNODES];
    __shared__ float sW1[64], sb1[64], sW2[128];
    const int tid = threadIdx.x;
    const int b = blockIdx.x;
    if (tid < 64) { sW1[tid] = W1[tid]; sb1[tid] = b1[tid]; }
    else if (tid < 192) sW2[tid - 64] = W2[tid - 64];
    if (tid < BNODES) {
        int v = rptr[b * BNODES + tid];
        sptr[tid] = v;
        cur[tid] = v;
    }
    if (tid == 0) sptr[BNODES] = gcur[b];
    __syncthreads();
    const int sz = sptr[BNODES];
    unsigned* base = packed + (size_t)b * BSTRIDE;
    const uint4* base4 = (const uint4*)base;
    const int nq4 = sz >> 2;
    // ---- placement pass (shared cursors; order within node arbitrary = OK) ----
    for (int j = tid; j < nq4; j += TPB) {
        uint4 p = base4[j];
        int pos;
        pos = atomicAdd(&cur[(p.x >> 17) & 127], 1); stage[pos] = p.x & 0x1FFFF;
        pos = atomicAdd(&cur[(p.y >> 17) & 127], 1); stage[pos] = p.y & 0x1FFFF;
        pos = atomicAdd(&cur[(p.z >> 17) & 127], 1); stage[pos] = p.z & 0x1FFFF;
        pos = atomicAdd(&cur[(p.w >> 17) & 127], 1); stage[pos] = p.w & 0x1FFFF;
    }
    for (int j = (nq4 << 2) + tid; j < sz; j += TPB) {
        unsigned p = base[j];
        int pos = atomicAdd(&cur[(p >> 17) & 127], 1);
        stage[pos] = p & 0x1FFFF;
    }
    __syncthreads();
    // ---- segmented sum of u[src] with src indices read FROM LDS ----
    int t = tid >> 2, k = tid & 3;
    int s0 = sptr[t], s1 = sptr[t + 1];
    float s = 0.f;
    int j = s0 + k;
    for (; j + 12 < s1; j += 16) {
        unsigned i0 = stage[j], i1 = stage[j + 4], i2 = stage[j + 8], i3 = stage[j + 12];
        float a0 = u[i0], a1 = u[i1], a2 = u[i2], a3 = u[i3];
        s += (a0 + a1) + (a2 + a3);
    }
    for (; j < s1; j += 4) s += u[stage[j]];
    s += __shfl_xor(s, 1, 64);
    s += __shfl_xor(s, 2, 64);
    int node = (b << BSHIFT) + t;
    if (k == 0 && node < N) {
        float di = dinv[node];
        float sv = di * (s + u[node]);           // self-loop term dinv*u
        float z0 = 0.f, z1 = 0.f;
        #pragma unroll
        for (int jj = 0; jj < 64; ++jj) {
            float h = fmaxf(fmaf(sv, sW1[jj], sb1[jj]), 0.f);
            z0 = fmaf(h, sW2[2 * jj], z0);
            z1 = fmaf(h, sW2[2 * jj + 1], z1);
        }
        w[node] = make_float2(di * z0, di * z1); // pre-scaled by dinv[src]
    }
    // ---- coalesced writeback of sorted srcs (consumed by k_agg2) ----
    for (int k2 = tid; k2 < sz; k2 += TPB) base[k2] = stage[k2];
}

// ---- layer-2: segmented float2 sum (4-way unrolled) + log_softmax + partial ----

__global__ __launch_bounds__(TPB) void k_agg2(const unsigned* __restrict__ sorted,
                                              const int* __restrict__ gcur,
                                              const int* __restrict__ rptr,
                                              const float* __restrict__ dinv,
                                              const float2* __restrict__ w,
                                              const float* __restrict__ b2,
                                              float* __restrict__ accum, int N) {
    __shared__ int sptr[BNODES + 1];
    int b = blockIdx.x;
    if (threadIdx.x < BNODES) sptr[threadIdx.x] = rptr[b * BNODES + threadIdx.x];
    if (threadIdx.x == 0) sptr[BNODES] = gcur[b];
    __syncthreads();
    int t = threadIdx.x >> 2, k = threadIdx.x & 3;
    const unsigned* base = sorted + (size_t)b * BSTRIDE;
    int s0 = sptr[t], s1 = sptr[t + 1];
    float sx = 0.f, sy = 0.f;
    int j = s0 + k;
    for (; j + 12 < s1; j += 16) {
        unsigned i0 = base[j], i1 = base[j + 4], i2 = base[j + 8], i3 = base[j + 12];
        float2 v0 = w[i0], v1 = w[i1], v2 = w[i2], v3 = w[i3];
        sx += (v0.x + v1.x) + (v2.x + v3.x);
        sy += (v0.y + v1.y) + (v2.y + v3.y);
    }
    for (; j < s1; j += 4) {
        float2 v = w[base[j]];
        sx += v.x;
        sy += v.y;
    }
    sx += __shfl_xor(sx, 1, 64); sx += __shfl_xor(sx, 2, 64);
    sy += __shfl_xor(sy, 1, 64); sy += __shfl_xor(sy, 2, 64);
    int node = (b << BSHIFT) + t;
    float l0 = 0.f, l1 = 0.f;
    if (k == 0 && node < N) {
        float di = dinv[node];
        float2 wi = w[node];
        float a0 = di * (sx + wi.x) + b2[0];
        float a1 = di * (sy + wi.y) + b2[1];
        float m = fmaxf(a0, a1);
        float lse = m + logf(expf(a0 - m) + expf(a1 - m));
        l0 = a0 - lse;
        l1 = a1 - lse;
    }
    #pragma unroll
    for (int off = 32; off > 0; off >>= 1) {
        l0 += __shfl_down(l0, off, 64);
        l1 += __shfl_down(l1, off, 64);
    }
    __shared__ float r0[TPB / 64], r1[TPB / 64];
    int wid = threadIdx.x >> 6, lane = threadIdx.x & 63;
    if (lane == 0) { r0[wid] = l0; r1[wid] = l1; }
    __syncthreads();
    if (threadIdx.x == 0) {
        float t0 = 0.f, t1 = 0.f;
        #pragma unroll
        for (int kk = 0; kk < TPB / 64; ++kk) { t0 += r0[kk]; t1 += r1[kk]; }
        accum[2 * b]     = t0;   // private slot, plain store, NO fence
        accum[2 * b + 1] = t1;
    }
}

// ---------------- final reduction over per-block partials ----------------

#define RTPB 1024
__global__ __launch_bounds__(RTPB) void k_reduce_final(const float* __restrict__ accum,
                                                       int nb, float* __restrict__ out,
                                                       float invN) {
    float t0 = 0.f, t1 = 0.f;
    for (int i = threadIdx.x; i < nb; i += RTPB) {
        t0 += accum[2 * i];
        t1 += accum[2 * i + 1];
    }
    #pragma unroll
    for (int off = 32; off > 0; off >>= 1) {
        t0 += __shfl_down(t0, off, 64);
        t1 += __shfl_down(t1, off, 64);
    }
    __shared__ float s0[RTPB / 64], s1[RTPB / 64];
    int wid = threadIdx.x >> 6, lane = threadIdx.x & 63;
    if (lane == 0) { s0[wid] = t0; s1[wid] = t1; }
    __syncthreads();
    if (threadIdx.x == 0) {
        float a = 0.f, b = 0.f;
        #pragma unroll
        for (int k = 0; k < RTPB / 64; ++k) { a += s0[k]; b += s1[k]; }
        out[0] = a * invN;
        out[1] = b * invN;
    }
}

__global__ void k_finalize(const float* __restrict__ accum, float* __restrict__ out, float invN) {
    out[0] = accum[0] * invN;
    out[1] = accum[1] * invN;
}

// ---------------- fallback (global-atomic path) ----------------

#define FTPB 256
__global__ void k_hist(const int* __restrict__ dst, int E, int* __restrict__ deg) {
    int e = blockIdx.x * FTPB + threadIdx.x;
    if (e < E) atomicAdd(&deg[dst[e]], 1);
}
__global__ void k_dinv_u(const int* __restrict__ deg, const float* __restrict__ x,
                         float* __restrict__ dinv, float* __restrict__ u, int N) {
    int i = blockIdx.x * FTPB + threadIdx.x;
    if (i < N) {
        float di = rsqrtf((float)(deg[i] + 1));
        dinv[i] = di;
        u[i] = di * x[i];
    }
}
__global__ void k_scatter1(const int* __restrict__ ei, int E,
                           const float* __restrict__ u, float* __restrict__ t) {
    int e = blockIdx.x * FTPB + threadIdx.x;
    if (e < E) atomicAdd(&t[ei[E + e]], u[ei[e]]);
}
__global__ void k_node_mid_fb(const float* __restrict__ dinv, const float* __restrict__ u,
                              const float* __restrict__ t,
                              const float* __restrict__ W1, const float* __restrict__ b1,
                              const float* __restrict__ W2, float2* __restrict__ w, int N) {
    __shared__ float sW1[64], sb1[64], sW2[128];
    if (threadIdx.x < 64) { sW1[threadIdx.x] = W1[threadIdx.x]; sb1[threadIdx.x] = b1[threadIdx.x]; }
    if (threadIdx.x < 128) sW2[threadIdx.x] = W2[threadIdx.x];
    __syncthreads();
    int i = blockIdx.x * FTPB + threadIdx.x;
    if (i < N) {
        float di = dinv[i];
        float s = di * (t[i] + u[i]);
        float z0 = 0.f, z1 = 0.f;
        #pragma unroll
        for (int j = 0; j < 64; ++j) {
            float h = fmaxf(fmaf(s, sW1[j], sb1[j]), 0.f);
            z0 = fmaf(h, sW2[2 * j], z0);
            z1 = fmaf(h, sW2[2 * j + 1], z1);
        }
        w[i] = make_float2(di * z0, di * z1);
    }
}
__global__ void k_scatter2(const int* __restrict__ ei, int E,
                           const float2* __restrict__ w, float* __restrict__ acc) {
    int e = blockIdx.x * FTPB + threadIdx.x;
    if (e < E) {
        float2 ws = w[ei[e]];
        int d = ei[E + e];
        atomicAdd(&acc[2 * d], ws.x);
        atomicAdd(&acc[2 * d + 1], ws.y);
    }
}
__global__ void k_node_out_fb(const float* __restrict__ dinv, const float2* __restrict__ w,
                              const float2* __restrict__ acc, const float* __restrict__ b2,
                              float* __restrict__ accum, int N) {
    int i = blockIdx.x * FTPB + threadIdx.x;
    float l0 = 0.f, l1 = 0.f;
    if (i < N) {
        float di = dinv[i];
        float2 a = acc[i];
        float2 ww = w[i];
        float a0 = di * (a.x + ww.x) + b2[0];
        float a1 = di * (a.y + ww.y) + b2[1];
        float m = fmaxf(a0, a1);
        float lse = m + logf(expf(a0 - m) + expf(a1 - m));
        l0 = a0 - lse;
        l1 = a1 - lse;
    }
    #pragma unroll
    for (int off = 32; off > 0; off >>= 1) {
        l0 += __shfl_down(l0, off, 64);
        l1 += __shfl_down(l1, off, 64);
    }
    __shared__ float s0[FTPB / 64], s1[FTPB / 64];
    int wid = threadIdx.x >> 6, lane = threadIdx.x & 63;
    if (lane == 0) { s0[wid] = l0; s1[wid] = l1; }
    __syncthreads();
    if (threadIdx.x == 0) {
        float t0 = 0.f, t1 = 0.f;
        #pragma unroll
        for (int k = 0; k < FTPB / 64; ++k) { t0 += s0[k]; t1 += s1[k]; }
        atomicAdd(&accum[0], t0);
        atomicAdd(&accum[1], t1);
    }
}

extern "C" void kernel_launch(void* const* d_in, const int* in_sizes, int n_in,
                              void* d_out, int out_size, void* d_ws, size_t ws_size,
                              hipStream_t stream) {
    const float* x  = (const float*)d_in[0];
    const int*   ei = (const int*)d_in[1];
    const float* W1 = (const float*)d_in[2];
    const float* b1 = (const float*)d_in[3];
    const float* W2 = (const float*)d_in[4];
    const float* b2 = (const float*)d_in[5];
    float* out = (float*)d_out;

    const int N = in_sizes[0];
    const int E = in_sizes[1] / 2;
    const int nbuck = (N + BNODES - 1) >> BSHIFT;
    const int gridN = (N + FTPB - 1) / FTPB;
    const int gridE = (E + FTPB - 1) / FTPB;

    size_t offPacked = 0;
    size_t offW      = offPacked + (size_t)nbuck * BSTRIDE * 4;
    size_t offDinv   = offW + (size_t)N * 8;
    size_t offU      = offDinv + (size_t)N * 4;
    size_t offGcur   = offU + (size_t)N * 4;
    size_t offAccum  = offGcur + (size_t)nbuck * 4;
    size_t offRptr   = offAccum + (size_t)2 * nbuck * 4;
    size_t need      = offRptr + (size_t)nbuck * BNODES * 4;

    if (ws_size >= need && nbuck <= MAXBUCK && N <= (1 << 17)) {
        unsigned* packed = (unsigned*)((char*)d_ws + offPacked);
        float2*   w      = (float2*)((char*)d_ws + offW);
        float*    dinv   = (float*)((char*)d_ws + offDinv);
        float*    u      = (float*)((char*)d_ws + offU);
        int*      gcur   = (int*)((char*)d_ws + offGcur);
        float*    accum  = (float*)((char*)d_ws + offAccum);
        int*      rptr   = (int*)((char*)d_ws + offRptr);

        hipMemsetAsync(gcur, 0, (size_t)nbuck * 4, stream);

        int epb = (((E + SORT_BLK - 1) / SORT_BLK) + 3) & ~3;

        k_sort<<<SORT_BLK, TPB, 0, stream>>>(ei, E, epb, nbuck, gcur, packed);
        k_count<<<nbuck, TPB, 0, stream>>>(packed, gcur, x, dinv, u, rptr, N);
        k_place_agg1<<<nbuck, TPB, 0, stream>>>(packed, gcur, rptr, dinv, u, W1, b1, W2, w, N);
        k_agg2<<<nbuck, TPB, 0, stream>>>(packed, gcur, rptr, dinv, (const float2*)w, b2, accum, N);
        k_reduce_final<<<1, RTPB, 0, stream>>>(accum, nbuck, out, 1.0f / (float)N);
    } else {
        int*   deg   = (int*)d_ws;
        float* t     = (float*)(deg + N);
        float* acc   = t + N;
        float* accum = acc + 2 * N;
        float* dinv  = accum + 2;
        float* u     = dinv + N;
        float2* w    = (float2*)(u + N);
        hipMemsetAsync(d_ws, 0, (size_t)(4 * N + 2) * sizeof(float), stream);
        k_hist<<<gridE, FTPB, 0, stream>>>(ei + E, E, deg);
        k_dinv_u<<<gridN, FTPB, 0, stream>>>(deg, x, dinv, u, N);
        k_scatter1<<<gridE, FTPB, 0, stream>>>(ei, E, u, t);
        k_node_mid_fb<<<gridN, FTPB, 0, stream>>>(dinv, u, t, W1, b1, W2, w, N);
        k_scatter2<<<gridE, FTPB, 0, stream>>>(ei, E, w, acc);
        k_node_out_fb<<<gridN, FTPB, 0, stream>>>(dinv, w, (const float2*)acc, b2, accum, N);
        k_finalize<<<1, 64, 0, stream>>>(accum, out, 1.0f / (float)N);
    }
}

// Round 15
// 156.356 us; speedup vs baseline: 1.0385x; 1.0057x over previous
//
#include <hip/hip_runtime.h>

// GCN 2-layer. R22 = R21 RESUBMITTED BYTE-IDENTICAL (infra-flake hypothesis).
// R21 failed twice with zero novel mechanisms in the diff vs R20 (which ran):
// agg2's placement loop is the same code that ran in place_agg1 (R20/R21),
// LDS ~26KB (fine), same launch shapes, no fences/coop/exotic blocks. Unlike
// R10 (grid.sync) and R15 (1024-thr blocks) there is nothing here that CAN
// hang. Verdict: broker flake; resubmit for the clean measurement.
// R21 change under test: remove the sorted-array round-trip. place_agg1's
// 12.8MB writeback existed only for agg2's read; agg2 re-places from packed
// itself (same read volume, shared-cursor placement R20-proven) -> the 12.8MB
// global WRITE disappears. Path traffic 39->26MB.
//  k_sort -> k_count -> k_place_agg1 (no writeback) -> k_agg2 (re-place) ->
//  k_reduce_final. No fences anywhere.
// packed word: bits[16:0]=src, bits[23:17]=dst&127 (packed is never rewritten).

#define TPB 512
#define SORT_BLK 256
#define BSHIFT 7
#define BNODES 128
#define MAXBUCK 1024
#define BSTRIDE 6144      // words per bucket region; mean 4092, sigma ~64 -> 32 sigma

// ---------------- bucket sort (count+place fused, atomic reservation) --------

__global__ __launch_bounds__(TPB) void k_sort(const int* __restrict__ ei, int E, int epb,
                                              int nbuck, int* __restrict__ gcur,
                                              unsigned* __restrict__ packed) {
    __shared__ int h[MAXBUCK];
    for (int b = threadIdx.x; b < nbuck; b += TPB) h[b] = 0;
    __syncthreads();
    const int4* d4 = (const int4*)(ei + E);
    int nq = epb >> 2;
    int q0 = blockIdx.x * nq;
    for (int j = threadIdx.x; j < nq; j += TPB) {
        int q = q0 + j;
        int e = q << 2;
        if (e + 3 < E) {
            int4 v = d4[q];
            atomicAdd(&h[v.x >> BSHIFT], 1);
            atomicAdd(&h[v.y >> BSHIFT], 1);
            atomicAdd(&h[v.z >> BSHIFT], 1);
            atomicAdd(&h[v.w >> BSHIFT], 1);
        } else {
            for (int k = 0; k < 4; ++k)
                if (e + k < E) atomicAdd(&h[(ei + E)[e + k] >> BSHIFT], 1);
        }
    }
    __syncthreads();
    for (int b = threadIdx.x; b < nbuck; b += TPB) {
        int c = h[b];
        h[b] = c ? atomicAdd(&gcur[b], c) : 0;
    }
    __syncthreads();
    const int4* s4 = (const int4*)ei;
    for (int j = threadIdx.x; j < nq; j += TPB) {
        int q = q0 + j;
        int e = q << 2;
        if (e + 3 < E) {
            int4 vs = s4[q];
            int4 vd = d4[q];
            int b, p;
            b = vd.x >> BSHIFT; p = atomicAdd(&h[b], 1);
            packed[b * BSTRIDE + p] = ((unsigned)(vd.x & (BNODES - 1)) << 17) | (unsigned)vs.x;
            b = vd.y >> BSHIFT; p = atomicAdd(&h[b], 1);
            packed[b * BSTRIDE + p] = ((unsigned)(vd.y & (BNODES - 1)) << 17) | (unsigned)vs.y;
            b = vd.z >> BSHIFT; p = atomicAdd(&h[b], 1);
            packed[b * BSTRIDE + p] = ((unsigned)(vd.z & (BNODES - 1)) << 17) | (unsigned)vs.z;
            b = vd.w >> BSHIFT; p = atomicAdd(&h[b], 1);
            packed[b * BSTRIDE + p] = ((unsigned)(vd.w & (BNODES - 1)) << 17) | (unsigned)vs.w;
        } else {
            for (int k = 0; k < 4; ++k) {
                int ee = e + k;
                if (ee < E) {
                    int s = ei[ee], d = ei[E + ee];
                    int b = d >> BSHIFT;
                    int p = atomicAdd(&h[b], 1);
                    packed[b * BSTRIDE + p] = ((unsigned)(d & (BNODES - 1)) << 17) | (unsigned)s;
                }
            }
        }
    }
}

// ------- per-bucket count -> rptr + dinv + u (no staging; tiny LDS) -------

__global__ __launch_bounds__(TPB) void k_count(const unsigned* __restrict__ packed,
                                               const int* __restrict__ gcur,
                                               const float* __restrict__ x,
                                               float* __restrict__ dinv,
                                               float* __restrict__ u,
                                               int* __restrict__ rptr, int N) {
    __shared__ int cnt[8][BNODES];
    __shared__ int eptr[BNODES];
    const int tid = threadIdx.x;
    for (int k = tid; k < 8 * BNODES; k += TPB) ((int*)cnt)[k] = 0;
    __syncthreads();
    const int b = blockIdx.x;
    const int sz = gcur[b];
    const unsigned* base = packed + (size_t)b * BSTRIDE;
    const uint4* base4 = (const uint4*)base;
    const int wv = tid >> 6;
    const int nq4 = sz >> 2;
    for (int j = tid; j < nq4; j += TPB) {
        uint4 p = base4[j];
        atomicAdd(&cnt[wv][(p.x >> 17) & 127], 1);
        atomicAdd(&cnt[wv][(p.y >> 17) & 127], 1);
        atomicAdd(&cnt[wv][(p.z >> 17) & 127], 1);
        atomicAdd(&cnt[wv][(p.w >> 17) & 127], 1);
    }
    for (int j = (nq4 << 2) + tid; j < sz; j += TPB)
        atomicAdd(&cnt[wv][(base[j] >> 17) & 127], 1);
    __syncthreads();
    int tot = 0;
    if (tid < BNODES) {
        #pragma unroll
        for (int c = 0; c < 8; ++c) tot += cnt[c][tid];
        eptr[tid] = tot;
    }
    __syncthreads();
    // ---- single-wave inclusive scan of 128 values ----
    if (tid < 64) {
        int v0 = eptr[tid], v1 = eptr[tid + 64];
        #pragma unroll
        for (int off = 1; off < 64; off <<= 1) {
            int t0 = __shfl_up(v0, off, 64);
            int t1 = __shfl_up(v1, off, 64);
            if (tid >= off) { v0 += t0; v1 += t1; }
        }
        v1 += __shfl(v0, 63, 64);
        eptr[tid] = v0;
        eptr[tid + 64] = v1;
    }
    __syncthreads();
    if (tid < BNODES) {
        int ex = eptr[tid] - tot;
        rptr[b * BNODES + tid] = ex;
        int node = (b << BSHIFT) + tid;
        if (node < N) {
            float di = rsqrtf((float)(tot + 1));   // +1 self-loop
            dinv[node] = di;
            u[node] = di * x[node];
        }
    }
}

// -- placement (shared cursors) + agg1 FROM LDS + MLP (no writeback) --

__global__ __launch_bounds__(TPB) void k_place_agg1(const unsigned* __restrict__ packed,
                                                    const int* __restrict__ gcur,
                                                    const int* __restrict__ rptr,
                                                    const float* __restrict__ dinv,
                                                    const float* __restrict__ u,
                                                    const float* __restrict__ W1,
                                                    const float* __restrict__ b1,
                                                    const float* __restrict__ W2,
                                                    float2* __restrict__ w, int N) {
    __shared__ unsigned stage[BSTRIDE];
    __shared__ int sptr[BNODES + 1];
    __shared__ int cur[BNODES];
    __shared__ float sW1[64], sb1[64], sW2[128];
    const int tid = threadIdx.x;
    const int b = blockIdx.x;
    if (tid < 64) { sW1[tid] = W1[tid]; sb1[tid] = b1[tid]; }
    else if (tid < 192) sW2[tid - 64] = W2[tid - 64];
    if (tid < BNODES) {
        int v = rptr[b * BNODES + tid];
        sptr[tid] = v;
        cur[tid] = v;
    }
    if (tid == 0) sptr[BNODES] = gcur[b];
    __syncthreads();
    const int sz = sptr[BNODES];
    const unsigned* base = packed + (size_t)b * BSTRIDE;
    const uint4* base4 = (const uint4*)base;
    const int nq4 = sz >> 2;
    // ---- placement pass (shared cursors; order within node arbitrary = OK) ----
    for (int j = tid; j < nq4; j += TPB) {
        uint4 p = base4[j];
        int pos;
        pos = atomicAdd(&cur[(p.x >> 17) & 127], 1); stage[pos] = p.x & 0x1FFFF;
        pos = atomicAdd(&cur[(p.y >> 17) & 127], 1); stage[pos] = p.y & 0x1FFFF;
        pos = atomicAdd(&cur[(p.z >> 17) & 127], 1); stage[pos] = p.z & 0x1FFFF;
        pos = atomicAdd(&cur[(p.w >> 17) & 127], 1); stage[pos] = p.w & 0x1FFFF;
    }
    for (int j = (nq4 << 2) + tid; j < sz; j += TPB) {
        unsigned p = base[j];
        int pos = atomicAdd(&cur[(p >> 17) & 127], 1);
        stage[pos] = p & 0x1FFFF;
    }
    __syncthreads();
    // ---- segmented sum of u[src] with src indices read FROM LDS ----
    int t = tid >> 2, k = tid & 3;
    int s0 = sptr[t], s1 = sptr[t + 1];
    float s = 0.f;
    int j = s0 + k;
    for (; j + 12 < s1; j += 16) {
        unsigned i0 = stage[j], i1 = stage[j + 4], i2 = stage[j + 8], i3 = stage[j + 12];
        float a0 = u[i0], a1 = u[i1], a2 = u[i2], a3 = u[i3];
        s += (a0 + a1) + (a2 + a3);
    }
    for (; j < s1; j += 4) s += u[stage[j]];
    s += __shfl_xor(s, 1, 64);
    s += __shfl_xor(s, 2, 64);
    int node = (b << BSHIFT) + t;
    if (k == 0 && node < N) {
        float di = dinv[node];
        float sv = di * (s + u[node]);           // self-loop term dinv*u
        float z0 = 0.f, z1 = 0.f;
        #pragma unroll
        for (int jj = 0; jj < 64; ++jj) {
            float h = fmaxf(fmaf(sv, sW1[jj], sb1[jj]), 0.f);
            z0 = fmaf(h, sW2[2 * jj], z0);
            z1 = fmaf(h, sW2[2 * jj + 1], z1);
        }
        w[node] = make_float2(di * z0, di * z1); // pre-scaled by dinv[src]
    }
    // no writeback: agg2 re-places from packed itself
}

// ---- layer-2: re-place from packed + float2 sum from LDS idx + log_softmax ----

__global__ __launch_bounds__(TPB) void k_agg2(const unsigned* __restrict__ packed,
                                              const int* __restrict__ gcur,
                                              const int* __restrict__ rptr,
                                              const float* __restrict__ dinv,
                                              const float2* __restrict__ w,
                                              const float* __restrict__ b2,
                                              float* __restrict__ accum, int N) {
    __shared__ unsigned stage[BSTRIDE];
    __shared__ int sptr[BNODES + 1];
    __shared__ int cur[BNODES];
    const int tid = threadIdx.x;
    const int b = blockIdx.x;
    if (tid < BNODES) {
        int v = rptr[b * BNODES + tid];
        sptr[tid] = v;
        cur[tid] = v;
    }
    if (tid == 0) sptr[BNODES] = gcur[b];
    __syncthreads();
    const int sz = sptr[BNODES];
    const unsigned* base = packed + (size_t)b * BSTRIDE;
    const uint4* base4 = (const uint4*)base;
    const int nq4 = sz >> 2;
    // ---- placement pass (identical mechanism to k_place_agg1) ----
    for (int j = tid; j < nq4; j += TPB) {
        uint4 p = base4[j];
        int pos;
        pos = atomicAdd(&cur[(p.x >> 17) & 127], 1); stage[pos] = p.x & 0x1FFFF;
        pos = atomicAdd(&cur[(p.y >> 17) & 127], 1); stage[pos] = p.y & 0x1FFFF;
        pos = atomicAdd(&cur[(p.z >> 17) & 127], 1); stage[pos] = p.z & 0x1FFFF;
        pos = atomicAdd(&cur[(p.w >> 17) & 127], 1); stage[pos] = p.w & 0x1FFFF;
    }
    for (int j = (nq4 << 2) + tid; j < sz; j += TPB) {
        unsigned p = base[j];
        int pos = atomicAdd(&cur[(p >> 17) & 127], 1);
        stage[pos] = p & 0x1FFFF;
    }
    __syncthreads();
    // ---- segmented float2 sum with src indices from LDS ----
    int t = tid >> 2, k = tid & 3;
    int s0 = sptr[t], s1 = sptr[t + 1];
    float sx = 0.f, sy = 0.f;
    int j = s0 + k;
    for (; j + 12 < s1; j += 16) {
        unsigned i0 = stage[j], i1 = stage[j + 4], i2 = stage[j + 8], i3 = stage[j + 12];
        float2 v0 = w[i0], v1 = w[i1], v2 = w[i2], v3 = w[i3];
        sx += (v0.x + v1.x) + (v2.x + v3.x);
        sy += (v0.y + v1.y) + (v2.y + v3.y);
    }
    for (; j < s1; j += 4) {
        float2 v = w[stage[j]];
        sx += v.x;
        sy += v.y;
    }
    sx += __shfl_xor(sx, 1, 64); sx += __shfl_xor(sx, 2, 64);
    sy += __shfl_xor(sy, 1, 64); sy += __shfl_xor(sy, 2, 64);
    int node = (b << BSHIFT) + t;
    float l0 = 0.f, l1 = 0.f;
    if (k == 0 && node < N) {
        float di = dinv[node];
        float2 wi = w[node];
        float a0 = di * (sx + wi.x) + b2[0];
        float a1 = di * (sy + wi.y) + b2[1];
        float m = fmaxf(a0, a1);
        float lse = m + logf(expf(a0 - m) + expf(a1 - m));
        l0 = a0 - lse;
        l1 = a1 - lse;
    }
    #pragma unroll
    for (int off = 32; off > 0; off >>= 1) {
        l0 += __shfl_down(l0, off, 64);
        l1 += __shfl_down(l1, off, 64);
    }
    __shared__ float r0[TPB / 64], r1[TPB / 64];
    int wid = tid >> 6, lane = tid & 63;
    if (lane == 0) { r0[wid] = l0; r1[wid] = l1; }
    __syncthreads();
    if (tid == 0) {
        float t0 = 0.f, t1 = 0.f;
        #pragma unroll
        for (int kk = 0; kk < TPB / 64; ++kk) { t0 += r0[kk]; t1 += r1[kk]; }
        accum[2 * b]     = t0;   // private slot, plain store, NO fence
        accum[2 * b + 1] = t1;
    }
}

// ---------------- final reduction over per-block partials ----------------

#define RTPB 1024
__global__ __launch_bounds__(RTPB) void k_reduce_final(const float* __restrict__ accum,
                                                       int nb, float* __restrict__ out,
                                                       float invN) {
    float t0 = 0.f, t1 = 0.f;
    for (int i = threadIdx.x; i < nb; i += RTPB) {
        t0 += accum[2 * i];
        t1 += accum[2 * i + 1];
    }
    #pragma unroll
    for (int off = 32; off > 0; off >>= 1) {
        t0 += __shfl_down(t0, off, 64);
        t1 += __shfl_down(t1, off, 64);
    }
    __shared__ float s0[RTPB / 64], s1[RTPB / 64];
    int wid = threadIdx.x >> 6, lane = threadIdx.x & 63;
    if (lane == 0) { s0[wid] = t0; s1[wid] = t1; }
    __syncthreads();
    if (threadIdx.x == 0) {
        float a = 0.f, b = 0.f;
        #pragma unroll
        for (int k = 0; k < RTPB / 64; ++k) { a += s0[k]; b += s1[k]; }
        out[0] = a * invN;
        out[1] = b * invN;
    }
}

__global__ void k_finalize(const float* __restrict__ accum, float* __restrict__ out, float invN) {
    out[0] = accum[0] * invN;
    out[1] = accum[1] * invN;
}

// ---------------- fallback (global-atomic path) ----------------

#define FTPB 256
__global__ void k_hist(const int* __restrict__ dst, int E, int* __restrict__ deg) {
    int e = blockIdx.x * FTPB + threadIdx.x;
    if (e < E) atomicAdd(&deg[dst[e]], 1);
}
__global__ void k_dinv_u(const int* __restrict__ deg, const float* __restrict__ x,
                         float* __restrict__ dinv, float* __restrict__ u, int N) {
    int i = blockIdx.x * FTPB + threadIdx.x;
    if (i < N) {
        float di = rsqrtf((float)(deg[i] + 1));
        dinv[i] = di;
        u[i] = di * x[i];
    }
}
__global__ void k_scatter1(const int* __restrict__ ei, int E,
                           const float* __restrict__ u, float* __restrict__ t) {
    int e = blockIdx.x * FTPB + threadIdx.x;
    if (e < E) atomicAdd(&t[ei[E + e]], u[ei[e]]);
}
__global__ void k_node_mid_fb(const float* __restrict__ dinv, const float* __restrict__ u,
                              const float* __restrict__ t,
                              const float* __restrict__ W1, const float* __restrict__ b1,
                              const float* __restrict__ W2, float2* __restrict__ w, int N) {
    __shared__ float sW1[64], sb1[64], sW2[128];
    if (threadIdx.x < 64) { sW1[threadIdx.x] = W1[threadIdx.x]; sb1[threadIdx.x] = b1[threadIdx.x]; }
    if (threadIdx.x < 128) sW2[threadIdx.x] = W2[threadIdx.x];
    __syncthreads();
    int i = blockIdx.x * FTPB + threadIdx.x;
    if (i < N) {
        float di = dinv[i];
        float s = di * (t[i] + u[i]);
        float z0 = 0.f, z1 = 0.f;
        #pragma unroll
        for (int j = 0; j < 64; ++j) {
            float h = fmaxf(fmaf(s, sW1[j], sb1[j]), 0.f);
            z0 = fmaf(h, sW2[2 * j], z0);
            z1 = fmaf(h, sW2[2 * j + 1], z1);
        }
        w[i] = make_float2(di * z0, di * z1);
    }
}
__global__ void k_scatter2(const int* __restrict__ ei, int E,
                           const float2* __restrict__ w, float* __restrict__ acc) {
    int e = blockIdx.x * FTPB + threadIdx.x;
    if (e < E) {
        float2 ws = w[ei[e]];
        int d = ei[E + e];
        atomicAdd(&acc[2 * d], ws.x);
        atomicAdd(&acc[2 * d + 1], ws.y);
    }
}
__global__ void k_node_out_fb(const float* __restrict__ dinv, const float2* __restrict__ w,
                              const float2* __restrict__ acc, const float* __restrict__ b2,
                              float* __restrict__ accum, int N) {
    int i = blockIdx.x * FTPB + threadIdx.x;
    float l0 = 0.f, l1 = 0.f;
    if (i < N) {
        float di = dinv[i];
        float2 a = acc[i];
        float2 ww = w[i];
        float a0 = di * (a.x + ww.x) + b2[0];
        float a1 = di * (a.y + ww.y) + b2[1];
        float m = fmaxf(a0, a1);
        float lse = m + logf(expf(a0 - m) + expf(a1 - m));
        l0 = a0 - lse;
        l1 = a1 - lse;
    }
    #pragma unroll
    for (int off = 32; off > 0; off >>= 1) {
        l0 += __shfl_down(l0, off, 64);
        l1 += __shfl_down(l1, off, 64);
    }
    __shared__ float s0[FTPB / 64], s1[FTPB / 64];
    int wid = threadIdx.x >> 6, lane = threadIdx.x & 63;
    if (lane == 0) { s0[wid] = l0; s1[wid] = l1; }
    __syncthreads();
    if (threadIdx.x == 0) {
        float t0 = 0.f, t1 = 0.f;
        #pragma unroll
        for (int k = 0; k < FTPB / 64; ++k) { t0 += s0[k]; t1 += s1[k]; }
        atomicAdd(&accum[0], t0);
        atomicAdd(&accum[1], t1);
    }
}

extern "C" void kernel_launch(void* const* d_in, const int* in_sizes, int n_in,
                              void* d_out, int out_size, void* d_ws, size_t ws_size,
                              hipStream_t stream) {
    const float* x  = (const float*)d_in[0];
    const int*   ei = (const int*)d_in[1];
    const float* W1 = (const float*)d_in[2];
    const float* b1 = (const float*)d_in[3];
    const float* W2 = (const float*)d_in[4];
    const float* b2 = (const float*)d_in[5];
    float* out = (float*)d_out;

    const int N = in_sizes[0];
    const int E = in_sizes[1] / 2;
    const int nbuck = (N + BNODES - 1) >> BSHIFT;
    const int gridN = (N + FTPB - 1) / FTPB;
    const int gridE = (E + FTPB - 1) / FTPB;

    size_t offPacked = 0;
    size_t offW      = offPacked + (size_t)nbuck * BSTRIDE * 4;
    size_t offDinv   = offW + (size_t)N * 8;
    size_t offU      = offDinv + (size_t)N * 4;
    size_t offGcur   = offU + (size_t)N * 4;
    size_t offAccum  = offGcur + (size_t)nbuck * 4;
    size_t offRptr   = offAccum + (size_t)2 * nbuck * 4;
    size_t need      = offRptr + (size_t)nbuck * BNODES * 4;

    if (ws_size >= need && nbuck <= MAXBUCK && N <= (1 << 17)) {
        unsigned* packed = (unsigned*)((char*)d_ws + offPacked);
        float2*   w      = (float2*)((char*)d_ws + offW);
        float*    dinv   = (float*)((char*)d_ws + offDinv);
        float*    u      = (float*)((char*)d_ws + offU);
        int*      gcur   = (int*)((char*)d_ws + offGcur);
        float*    accum  = (float*)((char*)d_ws + offAccum);
        int*      rptr   = (int*)((char*)d_ws + offRptr);

        hipMemsetAsync(gcur, 0, (size_t)nbuck * 4, stream);

        int epb = (((E + SORT_BLK - 1) / SORT_BLK) + 3) & ~3;

        k_sort<<<SORT_BLK, TPB, 0, stream>>>(ei, E, epb, nbuck, gcur, packed);
        k_count<<<nbuck, TPB, 0, stream>>>(packed, gcur, x, dinv, u, rptr, N);
        k_place_agg1<<<nbuck, TPB, 0, stream>>>(packed, gcur, rptr, dinv, u, W1, b1, W2, w, N);
        k_agg2<<<nbuck, TPB, 0, stream>>>(packed, gcur, rptr, dinv, (const float2*)w, b2, accum, N);
        k_reduce_final<<<1, RTPB, 0, stream>>>(accum, nbuck, out, 1.0f / (float)N);
    } else {
        int*   deg   = (int*)d_ws;
        float* t     = (float*)(deg + N);
        float* acc   = t + N;
        float* accum = acc + 2 * N;
        float* dinv  = accum + 2;
        float* u     = dinv + N;
        float2* w    = (float2*)(u + N);
        hipMemsetAsync(d_ws, 0, (size_t)(4 * N + 2) * sizeof(float), stream);
        k_hist<<<gridE, FTPB, 0, stream>>>(ei + E, E, deg);
        k_dinv_u<<<gridN, FTPB, 0, stream>>>(deg, x, dinv, u, N);
        k_scatter1<<<gridE, FTPB, 0, stream>>>(ei, E, u, t);
        k_node_mid_fb<<<gridN, FTPB, 0, stream>>>(dinv, u, t, W1, b1, W2, w, N);
        k_scatter2<<<gridE, FTPB, 0, stream>>>(ei, E, w, acc);
        k_node_out_fb<<<gridN, FTPB, 0, stream>>>(dinv, w, (const float2*)acc, b2, accum, N);
        k_finalize<<<1, 64, 0, stream>>>(accum, out, 1.0f / (float)N);
    }
}